// Round 6
// baseline (10448.746 us; speedup 1.0000x reference)
//
#include <hip/hip_runtime.h>
#include <hip/hip_bf16.h>

// MD-LSTM (4-dir 2D LSTM) + fused 1x1 conv. Round 6: f32 VALU GEMM
// (round-2-proven numerics) in the round-5 skeleton. Decides whether the
// 0.145 error floor of rounds 3-5 is structural (skeleton) or MFMA-numeric.
// B=32, C=32, H=W=64, HD=128, IN_DIM=288, Z=5*HD=640, OUT=128.
//
// Step block: 2 cells (64 rows) x 64 z-cols x 5 gates, 256 threads,
// 80 f32 acc/thread (8 rows x 2 cols x 5 gates). K=288 staged in LDS
// (concat x | h_up | h_left per row). W read from L2, coalesced float2.
// h/c in f32 parity buffers; 1x1 conv for diag s-1 fused as extra blocks.

#define HDIM 128
#define ZDIM 640
#define KDIM 288

__device__ __forceinline__ float sigmoidf_(float v) {
    return 1.0f / (1.0f + __expf(-v));
}
__device__ __forceinline__ float tanhf_(float v) {
    return 1.0f - 2.0f / (__expf(2.0f * v) + 1.0f);
}

// ---------------------------------------------------------------------------
// One-time transposes (f32):
//   Wt[d][k][n] = W_lin[d][n][k]   (4 x 288 x 640)
//   Wct[c][o]   = W_conv[o][c]     (512 x 128)
// ---------------------------------------------------------------------------
__global__ void prep_weights(const float* __restrict__ W_lin,
                             const float* __restrict__ W_conv,
                             float* __restrict__ Wt, float* __restrict__ Wct) {
    int idx = blockIdx.x * 256 + threadIdx.x;
    const int NLIN = 4 * ZDIM * KDIM;  // 737280
    if (idx < NLIN) {
        int d = idx / (ZDIM * KDIM);
        int r = idx % (ZDIM * KDIM);
        int n = r / KDIM;
        int k = r % KDIM;
        Wt[d * (ZDIM * KDIM) + k * ZDIM + n] = W_lin[idx];
    } else {
        int idx2 = idx - NLIN;
        if (idx2 < 128 * 512) {
            int o = idx2 / 512, c = idx2 % 512;
            Wct[c * 128 + o] = W_conv[idx2];
        }
    }
}

// x (32,32,64,64) -> x_t[ij][b*32+c]  (4096 x 1024) f32
__global__ __launch_bounds__(256) void transpose_x(const float* __restrict__ x,
                                                   float* __restrict__ x_t) {
    __shared__ float tile[64][65];
    int tb = blockIdx.x >> 6;  // bc-tile 0..15
    int tj = blockIdx.x & 63;  // ij-tile 0..63
    int t = threadIdx.x;
    for (int f = t; f < 4096; f += 256) {
        int r = f >> 6, cix = f & 63;
        tile[r][cix] = x[(size_t)(tb * 64 + r) * 4096 + tj * 64 + cix];
    }
    __syncthreads();
    for (int f = t; f < 4096; f += 256) {
        int rr = f >> 6, cc = f & 63;
        x_t[(size_t)(tj * 64 + rr) * 1024 + tb * 64 + cc] = tile[cc][rr];
    }
}

__global__ void fill_sentinel(float* __restrict__ out) {
    out[blockIdx.x * 256 + threadIdx.x] = 1.0e6f;
}

// ---------------------------------------------------------------------------
// Fused diagonal kernel.
//  blocks [0,nstep): step blocks, blk = (d*mt + mtile)*2 + cbt.
//    block = 2 cells (64 rows) x 64 cols (cbt half) x 5 gates.
//    thread t: rowgroup rg=t>>5 (8 rows rg*8..), col pair c2=t&31
//    -> acc[8][2][5]. K-loop: inp (LDS, 64x288) x Wt (L2).
//  blocks [nstep,nstep+4*ncp): 1x1 conv for diagonal s-1.
// ---------------------------------------------------------------------------
__global__ __launch_bounds__(256) void fused_step(
    const float* __restrict__ x_t,     // (4096,1024)
    const float* __restrict__ Wt,      // (4,288,640)
    const float* __restrict__ b_lin,   // (4,640)
    const float* __restrict__ Wci, const float* __restrict__ Wf1,
    const float* __restrict__ Wf2, const float* __restrict__ Wco,
    const float* __restrict__ Wct,     // (512,128)
    const float* __restrict__ b_conv,  // (128)
    float* __restrict__ h_par,         // (2,4,64,32,128) f32
    float* __restrict__ c_par,         // (2,4,64,32,128) f32
    float* __restrict__ out,           // (32,128,64,64)
    int s, int i0, int nc, int mt, int i0p, int ncp, int nstep) {
    __shared__ __align__(16) float smem[64 * KDIM];  // 73728 B

    const int t = threadIdx.x;
    const int blk = blockIdx.x;
    const int par = s & 1, parR = par ^ 1;

    if (blk < nstep) {
        // ---------------- step block ----------------
        int r0 = blk;
        const int cbt = r0 & 1;
        r0 >>= 1;
        const int mtile = r0 % mt;
        const int d = r0 / mt;

        const size_t slotR = (size_t)(parR * 4 + d) * 64;
        const size_t slotW = (size_t)(par * 4 + d) * 64;

        // cell info for both sub-cells
        int ivec[2], jvec[2], ijf[2];
        bool val[2];
#pragma unroll
        for (int cs = 0; cs < 2; ++cs) {
            int ct = mtile * 2 + cs;
            val[cs] = ct < nc;
            int i = i0 + ct, j = s - i;
            ivec[cs] = i;
            jvec[cs] = j;
            int fi = (d & 1) ? 63 - i : i;
            int fj = (d & 2) ? 63 - j : j;
            ijf[cs] = fi * 64 + fj;
        }

        // ---- stage inp[64][288] ----
        // x part: 64 rows x 32 k = 512 float4
        for (int f = t; f < 512; f += 256) {
            int row = f >> 3, k4 = f & 7;
            int cs = row >> 5, b = row & 31;
            float4 v = make_float4(0.f, 0.f, 0.f, 0.f);
            if (val[cs])
                v = *(const float4*)(x_t + (size_t)ijf[cs] * 1024 + b * 32 +
                                     k4 * 4);
            *(float4*)&smem[row * KDIM + k4 * 4] = v;
        }
        // h_up part: 64 rows x 128 k = 2048 float4
        for (int f = t; f < 2048; f += 256) {
            int row = f >> 5, k4 = f & 31;
            int cs = row >> 5, b = row & 31;
            float4 v = make_float4(0.f, 0.f, 0.f, 0.f);
            if (val[cs] && ivec[cs] > 0)
                v = *(const float4*)(h_par +
                                     (slotR + (size_t)(ivec[cs] - 1)) * 4096 +
                                     b * 128 + k4 * 4);
            *(float4*)&smem[row * KDIM + 32 + k4 * 4] = v;
        }
        // h_left part: 64 rows x 128 k
        for (int f = t; f < 2048; f += 256) {
            int row = f >> 5, k4 = f & 31;
            int cs = row >> 5, b = row & 31;
            float4 v = make_float4(0.f, 0.f, 0.f, 0.f);
            if (val[cs] && jvec[cs] > 0)
                v = *(const float4*)(h_par + (slotR + (size_t)ivec[cs]) * 4096 +
                                     b * 128 + k4 * 4);
            *(float4*)&smem[row * KDIM + 160 + k4 * 4] = v;
        }
        __syncthreads();

        // ---- GEMM: 8 rows x 2 cols x 5 gates per thread ----
        const int rg = t >> 5;        // rowgroup: rows rg*8 .. rg*8+7
        const int c2 = t & 31;        // col pair
        const int cb0 = cbt * 64 + c2 * 2;  // first of 2 cb-cols
        const float* wbase = Wt + (size_t)d * (KDIM * ZDIM);
        const float* xrow = smem + (rg * 8) * KDIM;

        float acc[8][2][5];
#pragma unroll
        for (int g = 0; g < 5; ++g) {
#pragma unroll
            for (int cc = 0; cc < 2; ++cc) {
                float bv = b_lin[d * ZDIM + g * 128 + cb0 + cc];
#pragma unroll
                for (int rr = 0; rr < 8; ++rr) acc[rr][cc][g] = bv;
            }
        }

#pragma unroll 2
        for (int k = 0; k < KDIM; ++k) {
            float xv[8];
#pragma unroll
            for (int rr = 0; rr < 8; ++rr) xv[rr] = xrow[rr * KDIM + k];
            const float* wk = wbase + (size_t)k * ZDIM + cb0;
            float wv[2][5];
#pragma unroll
            for (int g = 0; g < 5; ++g) {
                float2 w2 = *(const float2*)(wk + g * 128);
                wv[0][g] = w2.x;
                wv[1][g] = w2.y;
            }
#pragma unroll
            for (int rr = 0; rr < 8; ++rr)
#pragma unroll
                for (int cc = 0; cc < 2; ++cc)
#pragma unroll
                    for (int g = 0; g < 5; ++g)
                        acc[rr][cc][g] =
                            fmaf(xv[rr], wv[cc][g], acc[rr][cc][g]);
        }

        // ---- gate math + state writes ----
        const int cs = rg >> 2;  // wave-uniform cell of this thread's rows
        if (val[cs]) {
            const int i = ivec[cs], j = jvec[cs];
            const size_t ru = (slotR + (size_t)(i - 1)) * 4096;
            const size_t rl = (slotR + (size_t)i) * 4096;
            const size_t wbase2 = (slotW + (size_t)i) * 4096;
#pragma unroll
            for (int cc = 0; cc < 2; ++cc) {
                int col = cb0 + cc;
                float wciv = Wci[d * HDIM + col];
                float wf1v = Wf1[d * HDIM + col];
                float wf2v = Wf2[d * HDIM + col];
                float wcov = Wco[d * HDIM + col];
#pragma unroll
                for (int rr = 0; rr < 8; ++rr) {
                    int b = (rg * 8 + rr) & 31;
                    float cu = (i > 0) ? c_par[ru + b * 128 + col] : 0.f;
                    float cl = (j > 0) ? c_par[rl + b * 128 + col] : 0.f;
                    float ig = sigmoidf_(acc[rr][cc][0] + wciv * (cu + cl));
                    float f1 = sigmoidf_(acc[rr][cc][1] + wf1v * cu);
                    float f2 = sigmoidf_(acc[rr][cc][2] + wf2v * cl);
                    float cn = f1 * cu + f2 * cl + ig * tanhf_(acc[rr][cc][3]);
                    float oo = sigmoidf_(acc[rr][cc][4] + wcov * cn);
                    float hn = oo * tanhf_(cn);
                    c_par[wbase2 + b * 128 + col] = cn;
                    h_par[wbase2 + b * 128 + col] = hn;
                }
            }
        }
    } else {
        // ---------------- fused conv block (diagonal s-1) ----------------
        int cb2 = blk - nstep;
        int btc = cb2 & 3, cip = cb2 >> 2;
        int ip = i0p + cip, jp = (s - 1) - ip;
        float* hs = smem;  // reuse: 8 x 512 f32

        for (int f = t; f < 1024; f += 256) {  // 1024 float4
            int dd = f >> 8, rem = f & 255;
            int bb = rem >> 5, k4 = rem & 31;
            float4 v = *(const float4*)(
                h_par + ((size_t)(parR * 4 + dd) * 64 + ip) * 4096 +
                (btc * 8 + bb) * 128 + k4 * 4);
            *(float4*)&hs[bb * 512 + dd * 128 + k4 * 4] = v;
        }
        __syncthreads();

        const int o = t & 127, half = t >> 7;
        float acc[4];
#pragma unroll
        for (int q = 0; q < 4; ++q) acc[q] = b_conv[o];
#pragma unroll 4
        for (int c = 0; c < 512; ++c) {
            float wv = Wct[c * 128 + o];
#pragma unroll
            for (int q = 0; q < 4; ++q)
                acc[q] = fmaf(hs[(half * 4 + q) * 512 + c], wv, acc[q]);
        }
#pragma unroll
        for (int q = 0; q < 4; ++q) {
            int b = btc * 8 + half * 4 + q;
            out[(size_t)(b * 128 + o) * 4096 + ip * 64 + jp] = acc[q];
        }
    }
}

// ---------------------------------------------------------------------------
extern "C" void kernel_launch(void* const* d_in, const int* in_sizes, int n_in,
                              void* d_out, int out_size, void* d_ws,
                              size_t ws_size, hipStream_t stream) {
    const float* x = (const float*)d_in[0];
    const float* W_lin = (const float*)d_in[1];
    const float* b_lin = (const float*)d_in[2];
    const float* Wci = (const float*)d_in[3];
    const float* Wf1 = (const float*)d_in[4];
    const float* Wf2 = (const float*)d_in[5];
    const float* Wco = (const float*)d_in[6];
    const float* W_conv = (const float*)d_in[7];
    const float* b_conv = (const float*)d_in[8];
    float* out = (float*)d_out;

    // workspace (floats), ~37 MB total (round-2-proven size)
    const size_t N_PAR = 2ull * 4 * 64 * 32 * 128;  // 2,097,152
    const size_t N_WT = 4ull * KDIM * ZDIM;         //   737,280
    const size_t N_WCT = 512ull * 128;              //    65,536
    const size_t N_XT = 4096ull * 1024;             // 4,194,304
    float* h_par = (float*)d_ws;
    float* c_par = h_par + N_PAR;
    float* Wt = c_par + N_PAR;
    float* Wct = Wt + N_WT;
    float* x_t = Wct + N_WCT;
    size_t need = (2 * N_PAR + N_WT + N_WCT + N_XT) * 4ull;
    if (ws_size < need) {  // visible failure signature: out = 1e6
        fill_sentinel<<<(out_size + 255) / 256, 256, 0, stream>>>(out);
        return;
    }

    prep_weights<<<3136, 256, 0, stream>>>(W_lin, W_conv, Wt, Wct);
    transpose_x<<<1024, 256, 0, stream>>>(x, x_t);

    for (int s = 0; s <= 127; ++s) {
        int i0 = 0, nc = 0, mt = 1;
        if (s <= 126) {
            i0 = s > 63 ? s - 63 : 0;
            int i1 = s < 63 ? s : 63;
            nc = i1 - i0 + 1;
            mt = (nc + 1) / 2;
        }
        int i0p = 0, ncp = 0;
        if (s >= 1) {
            int sp = s - 1;
            i0p = sp > 63 ? sp - 63 : 0;
            int i1p = sp < 63 ? sp : 63;
            ncp = i1p - i0p + 1;
        }
        int nstep = (s <= 126) ? 4 * mt * 2 : 0;
        int nconv = 4 * ncp;
        fused_step<<<nstep + nconv, 256, 0, stream>>>(
            x_t, Wt, b_lin, Wci, Wf1, Wf2, Wco, Wct, b_conv, h_par, c_par, out,
            s, i0, nc, mt, i0p, ncp, nstep);
    }
}

// Round 7
// 9498.233 us; speedup vs baseline: 1.1001x; 1.1001x over previous
//
#include <hip/hip_runtime.h>
#include <hip/hip_bf16.h>

// MD-LSTM (4-dir 2D LSTM) + fused 1x1 conv. Round 7: f32 VALU optimized —
// 1-cell blocks (36.9KB LDS, 4 blocks/CU), f32x2 packed FMA (v_pk_fma_f32),
// 4x less serial depth per thread. Numerics identical to round 6 (passed
// at 0.0156): per-column k-sequential f32 accumulation.
// B=32, C=32, H=W=64, HD=128, IN_DIM=288, Z=5*HD=640, OUT=128.

#define HDIM 128
#define ZDIM 640
#define KDIM 288

typedef __attribute__((ext_vector_type(2))) float f32x2;

__device__ __forceinline__ float sigmoidf_(float v) {
    return 1.0f / (1.0f + __expf(-v));
}
__device__ __forceinline__ float tanhf_(float v) {
    return 1.0f - 2.0f / (__expf(2.0f * v) + 1.0f);
}

// ---------------------------------------------------------------------------
// One-time transposes (f32):
//   Wt[d][k][n] = W_lin[d][n][k]   (4 x 288 x 640)
//   Wct[c][o]   = W_conv[o][c]     (512 x 128)
// ---------------------------------------------------------------------------
__global__ void prep_weights(const float* __restrict__ W_lin,
                             const float* __restrict__ W_conv,
                             float* __restrict__ Wt, float* __restrict__ Wct) {
    int idx = blockIdx.x * 256 + threadIdx.x;
    const int NLIN = 4 * ZDIM * KDIM;  // 737280
    if (idx < NLIN) {
        int d = idx / (ZDIM * KDIM);
        int r = idx % (ZDIM * KDIM);
        int n = r / KDIM;
        int k = r % KDIM;
        Wt[d * (ZDIM * KDIM) + k * ZDIM + n] = W_lin[idx];
    } else {
        int idx2 = idx - NLIN;
        if (idx2 < 128 * 512) {
            int o = idx2 / 512, c = idx2 % 512;
            Wct[c * 128 + o] = W_conv[idx2];
        }
    }
}

// x (32,32,64,64) -> x_t[ij][b*32+c]  (4096 x 1024) f32
__global__ __launch_bounds__(256) void transpose_x(const float* __restrict__ x,
                                                   float* __restrict__ x_t) {
    __shared__ float tile[64][65];
    int tb = blockIdx.x >> 6;  // bc-tile 0..15
    int tj = blockIdx.x & 63;  // ij-tile 0..63
    int t = threadIdx.x;
    for (int f = t; f < 4096; f += 256) {
        int r = f >> 6, cix = f & 63;
        tile[r][cix] = x[(size_t)(tb * 64 + r) * 4096 + tj * 64 + cix];
    }
    __syncthreads();
    for (int f = t; f < 4096; f += 256) {
        int rr = f >> 6, cc = f & 63;
        x_t[(size_t)(tj * 64 + rr) * 1024 + tb * 64 + cc] = tile[cc][rr];
    }
}

__global__ void fill_sentinel(float* __restrict__ out) {
    out[blockIdx.x * 256 + threadIdx.x] = 1.0e6f;
}

// ---------------------------------------------------------------------------
// Fused diagonal kernel.
//  blocks [0,nstep): step blocks, blk = (d*nc + ci)*2 + cbt.
//    block = 1 cell (32 batch rows) x 64 z-cols (cbt half) x 5 gates.
//    thread t: rg=t>>5 (4 rows rg*4..), c2=t&31 (col pair cbt*64+c2*2)
//    -> acc[4][5] f32x2. K=288 staged in LDS (x | h_up | h_left).
//  blocks [nstep,nstep+4*ncp): 1x1 conv for diagonal s-1.
// ---------------------------------------------------------------------------
__global__ __launch_bounds__(256) void fused_step(
    const float* __restrict__ x_t,     // (4096,1024)
    const float* __restrict__ Wt,      // (4,288,640)
    const float* __restrict__ b_lin,   // (4,640)
    const float* __restrict__ Wci, const float* __restrict__ Wf1,
    const float* __restrict__ Wf2, const float* __restrict__ Wco,
    const float* __restrict__ Wct,     // (512,128)
    const float* __restrict__ b_conv,  // (128)
    float* __restrict__ h_par,         // (2,4,64,32,128) f32
    float* __restrict__ c_par,         // (2,4,64,32,128) f32
    float* __restrict__ out,           // (32,128,64,64)
    int s, int i0, int nc, int i0p, int ncp, int nstep) {
    __shared__ __align__(16) float smem[32 * KDIM];  // 36864 B

    const int t = threadIdx.x;
    const int blk = blockIdx.x;
    const int par = s & 1, parR = par ^ 1;

    if (blk < nstep) {
        // ---------------- step block (1 cell) ----------------
        int r0 = blk;
        const int cbt = r0 & 1;
        r0 >>= 1;
        const int ci = r0 % nc;
        const int d = r0 / nc;
        const int i = i0 + ci, j = s - i;
        const int fi = (d & 1) ? 63 - i : i;
        const int fj = (d & 2) ? 63 - j : j;
        const int ijf = fi * 64 + fj;

        const size_t slotR = (size_t)(parR * 4 + d) * 64;
        const size_t slotW = (size_t)(par * 4 + d) * 64;

        // ---- stage inp[32][288] : 9 float4 per thread ----
        {  // x part: 32 rows x 32 k = 256 float4
            int row = t >> 3, q = t & 7;
            *(float4*)&smem[row * KDIM + q * 4] =
                *(const float4*)(x_t + (size_t)ijf * 1024 + row * 32 + q * 4);
        }
        {  // h_up: 32 rows x 128 k = 1024 float4
            const float* hu =
                (i > 0) ? h_par + (slotR + (size_t)(i - 1)) * 4096 : nullptr;
            for (int f = t; f < 1024; f += 256) {
                int row = f >> 5, q = f & 31;
                float4 v = make_float4(0.f, 0.f, 0.f, 0.f);
                if (hu) v = *(const float4*)(hu + row * 128 + q * 4);
                *(float4*)&smem[row * KDIM + 32 + q * 4] = v;
            }
        }
        {  // h_left: 32 rows x 128 k
            const float* hl =
                (j > 0) ? h_par + (slotR + (size_t)i) * 4096 : nullptr;
            for (int f = t; f < 1024; f += 256) {
                int row = f >> 5, q = f & 31;
                float4 v = make_float4(0.f, 0.f, 0.f, 0.f);
                if (hl) v = *(const float4*)(hl + row * 128 + q * 4);
                *(float4*)&smem[row * KDIM + 160 + q * 4] = v;
            }
        }
        __syncthreads();

        // ---- GEMM: 4 rows x (2 cols packed) x 5 gates per thread ----
        const int rg = t >> 5;              // rowgroup: rows rg*4 .. rg*4+3
        const int c2 = t & 31;              // col pair index
        const int cb0 = cbt * 64 + c2 * 2;  // first of 2 z-cols
        const float* wdp = Wt + (size_t)d * (KDIM * ZDIM) + cb0;
        const float* xrow = smem + (rg * 4) * KDIM;

        f32x2 acc[4][5];
#pragma unroll
        for (int g = 0; g < 5; ++g) {
            f32x2 bv = *(const f32x2*)(b_lin + d * ZDIM + g * 128 + cb0);
#pragma unroll
            for (int rr = 0; rr < 4; ++rr) acc[rr][g] = bv;
        }

#pragma unroll 4
        for (int k = 0; k < KDIM; ++k) {
            const float* wk = wdp + (size_t)k * ZDIM;
            f32x2 wv[5];
#pragma unroll
            for (int g = 0; g < 5; ++g) wv[g] = *(const f32x2*)(wk + g * 128);
#pragma unroll
            for (int rr = 0; rr < 4; ++rr) {
                float xs = xrow[rr * KDIM + k];
                f32x2 xv = {xs, xs};
#pragma unroll
                for (int g = 0; g < 5; ++g)
                    acc[rr][g] += xv * wv[g];  // v_pk_fma_f32 (contraction)
            }
        }

        // ---- gate math + state writes ----
        const size_t ru = (slotR + (size_t)(i - 1)) * 4096;
        const size_t rl = (slotR + (size_t)i) * 4096;
        const size_t wb = (slotW + (size_t)i) * 4096;
#pragma unroll
        for (int cc = 0; cc < 2; ++cc) {
            const int col = cb0 + cc;
            const float wciv = Wci[d * HDIM + col];
            const float wf1v = Wf1[d * HDIM + col];
            const float wf2v = Wf2[d * HDIM + col];
            const float wcov = Wco[d * HDIM + col];
#pragma unroll
            for (int rr = 0; rr < 4; ++rr) {
                const int b = rg * 4 + rr;
                float cu = (i > 0) ? c_par[ru + b * 128 + col] : 0.f;
                float cl = (j > 0) ? c_par[rl + b * 128 + col] : 0.f;
                float ig = sigmoidf_(acc[rr][0][cc] + wciv * (cu + cl));
                float f1 = sigmoidf_(acc[rr][1][cc] + wf1v * cu);
                float f2 = sigmoidf_(acc[rr][2][cc] + wf2v * cl);
                float cn = f1 * cu + f2 * cl + ig * tanhf_(acc[rr][3][cc]);
                float oo = sigmoidf_(acc[rr][4][cc] + wcov * cn);
                float hn = oo * tanhf_(cn);
                c_par[wb + b * 128 + col] = cn;
                h_par[wb + b * 128 + col] = hn;
            }
        }
    } else {
        // ---------------- fused conv block (diagonal s-1) ----------------
        int cb2 = blk - nstep;
        int btc = cb2 & 3, cip = cb2 >> 2;
        int ip = i0p + cip, jp = (s - 1) - ip;
        float* hs = smem;  // reuse: 8 x 512 f32 (16 KB)

        for (int f = t; f < 1024; f += 256) {  // 1024 float4
            int dd = f >> 8, rem = f & 255;
            int bb = rem >> 5, k4 = rem & 31;
            float4 v = *(const float4*)(
                h_par + ((size_t)(parR * 4 + dd) * 64 + ip) * 4096 +
                (btc * 8 + bb) * 128 + k4 * 4);
            *(float4*)&hs[bb * 512 + dd * 128 + k4 * 4] = v;
        }
        __syncthreads();

        const int o = t & 127, half = t >> 7;
        float acc[4];
#pragma unroll
        for (int q = 0; q < 4; ++q) acc[q] = b_conv[o];
#pragma unroll 4
        for (int c = 0; c < 512; ++c) {
            float wv = Wct[c * 128 + o];
#pragma unroll
            for (int q = 0; q < 4; ++q)
                acc[q] = fmaf(hs[(half * 4 + q) * 512 + c], wv, acc[q]);
        }
#pragma unroll
        for (int q = 0; q < 4; ++q) {
            int b = btc * 8 + half * 4 + q;
            out[(size_t)(b * 128 + o) * 4096 + ip * 64 + jp] = acc[q];
        }
    }
}

// ---------------------------------------------------------------------------
extern "C" void kernel_launch(void* const* d_in, const int* in_sizes, int n_in,
                              void* d_out, int out_size, void* d_ws,
                              size_t ws_size, hipStream_t stream) {
    const float* x = (const float*)d_in[0];
    const float* W_lin = (const float*)d_in[1];
    const float* b_lin = (const float*)d_in[2];
    const float* Wci = (const float*)d_in[3];
    const float* Wf1 = (const float*)d_in[4];
    const float* Wf2 = (const float*)d_in[5];
    const float* Wco = (const float*)d_in[6];
    const float* W_conv = (const float*)d_in[7];
    const float* b_conv = (const float*)d_in[8];
    float* out = (float*)d_out;

    // workspace (floats), ~37 MB (round-2/6-proven size)
    const size_t N_PAR = 2ull * 4 * 64 * 32 * 128;  // 2,097,152
    const size_t N_WT = 4ull * KDIM * ZDIM;         //   737,280
    const size_t N_WCT = 512ull * 128;              //    65,536
    const size_t N_XT = 4096ull * 1024;             // 4,194,304
    float* h_par = (float*)d_ws;
    float* c_par = h_par + N_PAR;
    float* Wt = c_par + N_PAR;
    float* Wct = Wt + N_WT;
    float* x_t = Wct + N_WCT;
    size_t need = (2 * N_PAR + N_WT + N_WCT + N_XT) * 4ull;
    if (ws_size < need) {  // visible failure signature: out = 1e6
        fill_sentinel<<<(out_size + 255) / 256, 256, 0, stream>>>(out);
        return;
    }

    prep_weights<<<3136, 256, 0, stream>>>(W_lin, W_conv, Wt, Wct);
    transpose_x<<<1024, 256, 0, stream>>>(x, x_t);

    for (int s = 0; s <= 127; ++s) {
        int i0 = 0, nc = 0;
        if (s <= 126) {
            i0 = s > 63 ? s - 63 : 0;
            int i1 = s < 63 ? s : 63;
            nc = i1 - i0 + 1;
        }
        int i0p = 0, ncp = 0;
        if (s >= 1) {
            int sp = s - 1;
            i0p = sp > 63 ? sp - 63 : 0;
            int i1p = sp < 63 ? sp : 63;
            ncp = i1p - i0p + 1;
        }
        int nstep = (s <= 126) ? 8 * nc : 0;
        int nconv = 4 * ncp;
        fused_step<<<nstep + nconv, 256, 0, stream>>>(
            x_t, Wt, b_lin, Wci, Wf1, Wf2, Wco, Wct, b_conv, h_par, c_par, out,
            s, i0, nc, i0p, ncp, nstep);
    }
}

// Round 8
// 8929.172 us; speedup vs baseline: 1.1702x; 1.0637x over previous
//
#include <hip/hip_runtime.h>
#include <hip/hip_bf16.h>

// MD-LSTM (4-dir 2D LSTM) + fused 1x1 conv. Round 8: f32 VALU, latency-
// optimized: 4-way cb split (16nc blocks -> 4 blocks/CU), paired-k W layout
// (float4 = 2 cols x 2 k), ds_read_b64 A reads, LDS stride 292.
// Numerics identical to rounds 6/7 (passed 0.015625): k-sequential f32.
// B=32, C=32, H=W=64, HD=128, IN_DIM=288, Z=5*HD=640, OUT=128.

#define HDIM 128
#define ZDIM 640
#define KDIM 288
#define K2DIM 144
#define ASTR 292  // A LDS row stride (floats): 16B-aligned, +4 banks/row

typedef __attribute__((ext_vector_type(2))) float f32x2;

__device__ __forceinline__ float sigmoidf_(float v) {
    return 1.0f / (1.0f + __expf(-v));
}
__device__ __forceinline__ float tanhf_(float v) {
    return 1.0f - 2.0f / (__expf(2.0f * v) + 1.0f);
}

// ---------------------------------------------------------------------------
// One-time transposes (f32):
//   Wt2[d][k/2][n][k&1] = W_lin[d][n][k]   (4 x 144 x 640 x 2)
//   Wct[c][o]           = W_conv[o][c]     (512 x 128)
// ---------------------------------------------------------------------------
__global__ void prep_weights(const float* __restrict__ W_lin,
                             const float* __restrict__ W_conv,
                             float* __restrict__ Wt2, float* __restrict__ Wct) {
    int idx = blockIdx.x * 256 + threadIdx.x;
    const int NLIN = 4 * ZDIM * KDIM;  // 737280
    if (idx < NLIN) {
        int d = idx / (ZDIM * KDIM);
        int r = idx % (ZDIM * KDIM);
        int n = r / KDIM;
        int k = r % KDIM;
        Wt2[((d * K2DIM + (k >> 1)) * ZDIM + n) * 2 + (k & 1)] = W_lin[idx];
    } else {
        int idx2 = idx - NLIN;
        if (idx2 < 128 * 512) {
            int o = idx2 / 512, c = idx2 % 512;
            Wct[c * 128 + o] = W_conv[idx2];
        }
    }
}

// x (32,32,64,64) -> x_t[ij][b*32+c]  (4096 x 1024) f32
__global__ __launch_bounds__(256) void transpose_x(const float* __restrict__ x,
                                                   float* __restrict__ x_t) {
    __shared__ float tile[64][65];
    int tb = blockIdx.x >> 6;  // bc-tile 0..15
    int tj = blockIdx.x & 63;  // ij-tile 0..63
    int t = threadIdx.x;
    for (int f = t; f < 4096; f += 256) {
        int r = f >> 6, cix = f & 63;
        tile[r][cix] = x[(size_t)(tb * 64 + r) * 4096 + tj * 64 + cix];
    }
    __syncthreads();
    for (int f = t; f < 4096; f += 256) {
        int rr = f >> 6, cc = f & 63;
        x_t[(size_t)(tj * 64 + rr) * 1024 + tb * 64 + cc] = tile[cc][rr];
    }
}

__global__ void fill_sentinel(float* __restrict__ out) {
    out[blockIdx.x * 256 + threadIdx.x] = 1.0e6f;
}

// ---------------------------------------------------------------------------
// Fused diagonal kernel.
//  blocks [0,nstep): step blocks, blk = ((d*nc + ci)<<2) + cbt.
//    block = 1 cell (32 rows) x 32 z-cols (quarter cbt) x 5 gates.
//    thread t: tr=t>>4 -> rows {2tr,2tr+1}; c2=t&15 -> col pair
//    cbt*32 + c2*2. acc[2][5] f32x2. K-loop over 144 k-pairs:
//    5 float4 W (2 cols x 2 k) + 2 ds_read_b64 A + 20 pk_fma.
//  blocks [nstep,nstep+4*ncp): 1x1 conv for diagonal s-1.
// ---------------------------------------------------------------------------
__global__ __launch_bounds__(256, 4) void fused_step(
    const float* __restrict__ x_t,     // (4096,1024)
    const float* __restrict__ Wt2,     // (4,144,640,2)
    const float* __restrict__ b_lin,   // (4,640)
    const float* __restrict__ Wci, const float* __restrict__ Wf1,
    const float* __restrict__ Wf2, const float* __restrict__ Wco,
    const float* __restrict__ Wct,     // (512,128)
    const float* __restrict__ b_conv,  // (128)
    float* __restrict__ h_par,         // (2,4,64,32,128) f32
    float* __restrict__ c_par,         // (2,4,64,32,128) f32
    float* __restrict__ out,           // (32,128,64,64)
    int s, int i0, int nc, int i0p, int ncp, int nstep) {
    __shared__ __align__(16) float smem[32 * ASTR];  // 37376 B

    const int t = threadIdx.x;
    const int blk = blockIdx.x;
    const int par = s & 1, parR = par ^ 1;

    if (blk < nstep) {
        // ---------------- step block (1 cell, 32-col quarter) ----------
        const int cbt = blk & 3;
        int r0 = blk >> 2;
        const int ci = r0 % nc;
        const int d = r0 / nc;
        const int i = i0 + ci, j = s - i;
        const int fi = (d & 1) ? 63 - i : i;
        const int fj = (d & 2) ? 63 - j : j;
        const int ijf = fi * 64 + fj;

        const size_t slotR = (size_t)(parR * 4 + d) * 64;
        const size_t slotW = (size_t)(par * 4 + d) * 64;

        // ---- stage A[32][288] (stride 292) ----
        {  // x part: 32 rows x 32 k = 256 float4
            int row = t >> 3, q = t & 7;
            *(float4*)&smem[row * ASTR + q * 4] =
                *(const float4*)(x_t + (size_t)ijf * 1024 + row * 32 + q * 4);
        }
        {  // h_up: k in [32,160)
            const float* hu =
                (i > 0) ? h_par + (slotR + (size_t)(i - 1)) * 4096 : nullptr;
            for (int f = t; f < 1024; f += 256) {
                int row = f >> 5, q = f & 31;
                float4 v = make_float4(0.f, 0.f, 0.f, 0.f);
                if (hu) v = *(const float4*)(hu + row * 128 + q * 4);
                *(float4*)&smem[row * ASTR + 32 + q * 4] = v;
            }
        }
        {  // h_left: k in [160,288)
            const float* hl =
                (j > 0) ? h_par + (slotR + (size_t)i) * 4096 : nullptr;
            for (int f = t; f < 1024; f += 256) {
                int row = f >> 5, q = f & 31;
                float4 v = make_float4(0.f, 0.f, 0.f, 0.f);
                if (hl) v = *(const float4*)(hl + row * 128 + q * 4);
                *(float4*)&smem[row * ASTR + 160 + q * 4] = v;
            }
        }
        __syncthreads();

        // ---- GEMM: 2 rows x 1 colpair x 5 gates per thread ----
        const int c2 = t & 15, tr = t >> 4;
        const int cb0 = cbt * 32 + c2 * 2;
        const float* wbase = Wt2 + (size_t)(d * K2DIM) * 1280 + cb0 * 2;
        const float* xr0 = smem + (2 * tr) * ASTR;
        const float* xr1 = xr0 + ASTR;

        f32x2 acc[2][5];
#pragma unroll
        for (int g = 0; g < 5; ++g) {
            f32x2 bv = *(const f32x2*)(b_lin + d * ZDIM + g * 128 + cb0);
            acc[0][g] = bv;
            acc[1][g] = bv;
        }

#pragma unroll 4
        for (int k2 = 0; k2 < K2DIM; ++k2) {
            const float* wk = wbase + (size_t)k2 * 1280;
            float4 wv[5];
#pragma unroll
            for (int g = 0; g < 5; ++g)
                wv[g] = *(const float4*)(wk + g * 256);
            f32x2 a0 = *(const f32x2*)(xr0 + k2 * 2);
            f32x2 a1 = *(const f32x2*)(xr1 + k2 * 2);
#pragma unroll
            for (int g = 0; g < 5; ++g) {
                f32x2 we = {wv[g].x, wv[g].z};  // k even, both cols
                f32x2 wo = {wv[g].y, wv[g].w};  // k odd
                acc[0][g] += f32x2{a0.x, a0.x} * we;
                acc[0][g] += f32x2{a0.y, a0.y} * wo;
                acc[1][g] += f32x2{a1.x, a1.x} * we;
                acc[1][g] += f32x2{a1.y, a1.y} * wo;
            }
        }

        // ---- gate math + state writes ----
        const size_t ru = (slotR + (size_t)(i - 1)) * 4096;
        const size_t rl = (slotR + (size_t)i) * 4096;
        const size_t wb = (slotW + (size_t)i) * 4096;
#pragma unroll
        for (int cc = 0; cc < 2; ++cc) {
            const int col = cb0 + cc;
            const float wciv = Wci[d * HDIM + col];
            const float wf1v = Wf1[d * HDIM + col];
            const float wf2v = Wf2[d * HDIM + col];
            const float wcov = Wco[d * HDIM + col];
#pragma unroll
            for (int rr = 0; rr < 2; ++rr) {
                const int b = 2 * tr + rr;
                float cu = (i > 0) ? c_par[ru + b * 128 + col] : 0.f;
                float cl = (j > 0) ? c_par[rl + b * 128 + col] : 0.f;
                float ig = sigmoidf_(acc[rr][0][cc] + wciv * (cu + cl));
                float f1 = sigmoidf_(acc[rr][1][cc] + wf1v * cu);
                float f2 = sigmoidf_(acc[rr][2][cc] + wf2v * cl);
                float cn = f1 * cu + f2 * cl + ig * tanhf_(acc[rr][3][cc]);
                float oo = sigmoidf_(acc[rr][4][cc] + wcov * cn);
                float hn = oo * tanhf_(cn);
                c_par[wb + b * 128 + col] = cn;
                h_par[wb + b * 128 + col] = hn;
            }
        }
    } else {
        // ---------------- fused conv block (diagonal s-1) ----------------
        int cb2 = blk - nstep;
        int btc = cb2 & 3, cip = cb2 >> 2;
        int ip = i0p + cip, jp = (s - 1) - ip;
        float* hs = smem;  // reuse: 8 x 512 f32 (16 KB)

        for (int f = t; f < 1024; f += 256) {  // 1024 float4
            int dd = f >> 8, rem = f & 255;
            int bb = rem >> 5, k4 = rem & 31;
            float4 v = *(const float4*)(
                h_par + ((size_t)(parR * 4 + dd) * 64 + ip) * 4096 +
                (btc * 8 + bb) * 128 + k4 * 4);
            *(float4*)&hs[bb * 512 + dd * 128 + k4 * 4] = v;
        }
        __syncthreads();

        const int o = t & 127, half = t >> 7;
        float acc[4];
#pragma unroll
        for (int q = 0; q < 4; ++q) acc[q] = b_conv[o];
#pragma unroll 4
        for (int c = 0; c < 512; ++c) {
            float wv = Wct[c * 128 + o];
#pragma unroll
            for (int q = 0; q < 4; ++q)
                acc[q] = fmaf(hs[(half * 4 + q) * 512 + c], wv, acc[q]);
        }
#pragma unroll
        for (int q = 0; q < 4; ++q) {
            int b = btc * 8 + half * 4 + q;
            out[(size_t)(b * 128 + o) * 4096 + ip * 64 + jp] = acc[q];
        }
    }
}

// ---------------------------------------------------------------------------
extern "C" void kernel_launch(void* const* d_in, const int* in_sizes, int n_in,
                              void* d_out, int out_size, void* d_ws,
                              size_t ws_size, hipStream_t stream) {
    const float* x = (const float*)d_in[0];
    const float* W_lin = (const float*)d_in[1];
    const float* b_lin = (const float*)d_in[2];
    const float* Wci = (const float*)d_in[3];
    const float* Wf1 = (const float*)d_in[4];
    const float* Wf2 = (const float*)d_in[5];
    const float* Wco = (const float*)d_in[6];
    const float* W_conv = (const float*)d_in[7];
    const float* b_conv = (const float*)d_in[8];
    float* out = (float*)d_out;

    // workspace (floats), ~37 MB (proven size)
    const size_t N_PAR = 2ull * 4 * 64 * 32 * 128;  // 2,097,152
    const size_t N_WT = 4ull * KDIM * ZDIM;         //   737,280
    const size_t N_WCT = 512ull * 128;              //    65,536
    const size_t N_XT = 4096ull * 1024;             // 4,194,304
    float* h_par = (float*)d_ws;
    float* c_par = h_par + N_PAR;
    float* Wt2 = c_par + N_PAR;
    float* Wct = Wt2 + N_WT;
    float* x_t = Wct + N_WCT;
    size_t need = (2 * N_PAR + N_WT + N_WCT + N_XT) * 4ull;
    if (ws_size < need) {  // visible failure signature: out = 1e6
        fill_sentinel<<<(out_size + 255) / 256, 256, 0, stream>>>(out);
        return;
    }

    prep_weights<<<3136, 256, 0, stream>>>(W_lin, W_conv, Wt2, Wct);
    transpose_x<<<1024, 256, 0, stream>>>(x, x_t);

    for (int s = 0; s <= 127; ++s) {
        int i0 = 0, nc = 0;
        if (s <= 126) {
            i0 = s > 63 ? s - 63 : 0;
            int i1 = s < 63 ? s : 63;
            nc = i1 - i0 + 1;
        }
        int i0p = 0, ncp = 0;
        if (s >= 1) {
            int sp = s - 1;
            i0p = sp > 63 ? sp - 63 : 0;
            int i1p = sp < 63 ? sp : 63;
            ncp = i1p - i0p + 1;
        }
        int nstep = (s <= 126) ? 16 * nc : 0;
        int nconv = 4 * ncp;
        fused_step<<<nstep + nconv, 256, 0, stream>>>(
            x_t, Wt2, b_lin, Wci, Wf1, Wf2, Wco, Wct, b_conv, h_par, c_par,
            out, s, i0, nc, i0p, ncp, nstep);
    }
}

// Round 9
// 8427.181 us; speedup vs baseline: 1.2399x; 1.0596x over previous
//
#include <hip/hip_runtime.h>
#include <hip/hip_bf16.h>

// MD-LSTM (4-dir 2D LSTM) + fused 1x1 conv. Round 9: round-8 structure +
// explicit 2-stage software pipeline in the k2-loop (prefetch W/A for k2+1
// while computing k2). Numerics bit-identical to rounds 6-8 (0.015625).
// B=32, C=32, H=W=64, HD=128, IN_DIM=288, Z=5*HD=640, OUT=128.

#define HDIM 128
#define ZDIM 640
#define KDIM 288
#define K2DIM 144
#define ASTR 292  // A LDS row stride (floats): 16B-aligned, +4 banks/row

typedef __attribute__((ext_vector_type(2))) float f32x2;

__device__ __forceinline__ float sigmoidf_(float v) {
    return 1.0f / (1.0f + __expf(-v));
}
__device__ __forceinline__ float tanhf_(float v) {
    return 1.0f - 2.0f / (__expf(2.0f * v) + 1.0f);
}

// ---------------------------------------------------------------------------
// One-time transposes (f32):
//   Wt2[d][k/2][n][k&1] = W_lin[d][n][k]   (4 x 144 x 640 x 2)
//   Wct[c][o]           = W_conv[o][c]     (512 x 128)
// ---------------------------------------------------------------------------
__global__ void prep_weights(const float* __restrict__ W_lin,
                             const float* __restrict__ W_conv,
                             float* __restrict__ Wt2, float* __restrict__ Wct) {
    int idx = blockIdx.x * 256 + threadIdx.x;
    const int NLIN = 4 * ZDIM * KDIM;  // 737280
    if (idx < NLIN) {
        int d = idx / (ZDIM * KDIM);
        int r = idx % (ZDIM * KDIM);
        int n = r / KDIM;
        int k = r % KDIM;
        Wt2[((d * K2DIM + (k >> 1)) * ZDIM + n) * 2 + (k & 1)] = W_lin[idx];
    } else {
        int idx2 = idx - NLIN;
        if (idx2 < 128 * 512) {
            int o = idx2 / 512, c = idx2 % 512;
            Wct[c * 128 + o] = W_conv[idx2];
        }
    }
}

// x (32,32,64,64) -> x_t[ij][b*32+c]  (4096 x 1024) f32
__global__ __launch_bounds__(256) void transpose_x(const float* __restrict__ x,
                                                   float* __restrict__ x_t) {
    __shared__ float tile[64][65];
    int tb = blockIdx.x >> 6;  // bc-tile 0..15
    int tj = blockIdx.x & 63;  // ij-tile 0..63
    int t = threadIdx.x;
    for (int f = t; f < 4096; f += 256) {
        int r = f >> 6, cix = f & 63;
        tile[r][cix] = x[(size_t)(tb * 64 + r) * 4096 + tj * 64 + cix];
    }
    __syncthreads();
    for (int f = t; f < 4096; f += 256) {
        int rr = f >> 6, cc = f & 63;
        x_t[(size_t)(tj * 64 + rr) * 1024 + tb * 64 + cc] = tile[cc][rr];
    }
}

__global__ void fill_sentinel(float* __restrict__ out) {
    out[blockIdx.x * 256 + threadIdx.x] = 1.0e6f;
}

// ---------------------------------------------------------------------------
// Fused diagonal kernel.
//  blocks [0,nstep): step blocks, blk = ((d*nc + ci)<<2) + cbt.
//    block = 1 cell (32 rows) x 32 z-cols x 5 gates. thread: tr=t>>4 ->
//    rows {2tr,2tr+1}; c2=t&15 -> col pair cbt*32+c2*2. acc[2][5] f32x2.
//    K-loop: 144 k-pairs, 2-stage ping-pong prefetch (W global, A LDS).
//  blocks [nstep,nstep+4*ncp): 1x1 conv for diagonal s-1.
// ---------------------------------------------------------------------------
__global__ __launch_bounds__(256, 4) void fused_step(
    const float* __restrict__ x_t,     // (4096,1024)
    const float* __restrict__ Wt2,     // (4,144,640,2)
    const float* __restrict__ b_lin,   // (4,640)
    const float* __restrict__ Wci, const float* __restrict__ Wf1,
    const float* __restrict__ Wf2, const float* __restrict__ Wco,
    const float* __restrict__ Wct,     // (512,128)
    const float* __restrict__ b_conv,  // (128)
    float* __restrict__ h_par,         // (2,4,64,32,128) f32
    float* __restrict__ c_par,         // (2,4,64,32,128) f32
    float* __restrict__ out,           // (32,128,64,64)
    int s, int i0, int nc, int i0p, int ncp, int nstep) {
    __shared__ __align__(16) float smem[32 * ASTR];  // 37376 B

    const int t = threadIdx.x;
    const int blk = blockIdx.x;
    const int par = s & 1, parR = par ^ 1;

    if (blk < nstep) {
        // ---------------- step block (1 cell, 32-col quarter) ----------
        const int cbt = blk & 3;
        int r0 = blk >> 2;
        const int ci = r0 % nc;
        const int d = r0 / nc;
        const int i = i0 + ci, j = s - i;
        const int fi = (d & 1) ? 63 - i : i;
        const int fj = (d & 2) ? 63 - j : j;
        const int ijf = fi * 64 + fj;

        const size_t slotR = (size_t)(parR * 4 + d) * 64;
        const size_t slotW = (size_t)(par * 4 + d) * 64;

        // ---- stage A[32][288] (stride 292) ----
        {  // x part: 32 rows x 32 k = 256 float4
            int row = t >> 3, q = t & 7;
            *(float4*)&smem[row * ASTR + q * 4] =
                *(const float4*)(x_t + (size_t)ijf * 1024 + row * 32 + q * 4);
        }
        {  // h_up: k in [32,160)
            const float* hu =
                (i > 0) ? h_par + (slotR + (size_t)(i - 1)) * 4096 : nullptr;
            for (int f = t; f < 1024; f += 256) {
                int row = f >> 5, q = f & 31;
                float4 v = make_float4(0.f, 0.f, 0.f, 0.f);
                if (hu) v = *(const float4*)(hu + row * 128 + q * 4);
                *(float4*)&smem[row * ASTR + 32 + q * 4] = v;
            }
        }
        {  // h_left: k in [160,288)
            const float* hl =
                (j > 0) ? h_par + (slotR + (size_t)i) * 4096 : nullptr;
            for (int f = t; f < 1024; f += 256) {
                int row = f >> 5, q = f & 31;
                float4 v = make_float4(0.f, 0.f, 0.f, 0.f);
                if (hl) v = *(const float4*)(hl + row * 128 + q * 4);
                *(float4*)&smem[row * ASTR + 160 + q * 4] = v;
            }
        }
        __syncthreads();

        // ---- GEMM: 2 rows x 1 colpair x 5 gates, ping-pong pipelined ----
        const int c2 = t & 15, tr = t >> 4;
        const int cb0 = cbt * 32 + c2 * 2;
        const float* wbase = Wt2 + (size_t)(d * K2DIM) * 1280 + cb0 * 2;
        const float* xr0 = smem + (2 * tr) * ASTR;
        const float* xr1 = xr0 + ASTR;

        f32x2 acc[2][5];
#pragma unroll
        for (int g = 0; g < 5; ++g) {
            f32x2 bv = *(const f32x2*)(b_lin + d * ZDIM + g * 128 + cb0);
            acc[0][g] = bv;
            acc[1][g] = bv;
        }

        float4 wva[5], wvb[5];
        f32x2 a0a, a1a, a0b, a1b;
        {  // preload k2 = 0 into set A
            const float* wk = wbase;
#pragma unroll
            for (int g = 0; g < 5; ++g) wva[g] = *(const float4*)(wk + g * 256);
            a0a = *(const f32x2*)(xr0);
            a1a = *(const f32x2*)(xr1);
        }

        for (int k2 = 0; k2 < K2DIM; k2 += 2) {
            // prefetch k2+1 into set B (K2DIM even -> always in range)
            {
                const float* wk = wbase + (size_t)(k2 + 1) * 1280;
#pragma unroll
                for (int g = 0; g < 5; ++g)
                    wvb[g] = *(const float4*)(wk + g * 256);
                a0b = *(const f32x2*)(xr0 + (k2 + 1) * 2);
                a1b = *(const f32x2*)(xr1 + (k2 + 1) * 2);
            }
            // compute k2 from set A
#pragma unroll
            for (int g = 0; g < 5; ++g) {
                f32x2 we = {wva[g].x, wva[g].z};
                f32x2 wo = {wva[g].y, wva[g].w};
                acc[0][g] += f32x2{a0a.x, a0a.x} * we;
                acc[0][g] += f32x2{a0a.y, a0a.y} * wo;
                acc[1][g] += f32x2{a1a.x, a1a.x} * we;
                acc[1][g] += f32x2{a1a.y, a1a.y} * wo;
            }
            // prefetch k2+2 into set A (last iter: harmless reload of 142)
            {
                int k2n = (k2 + 2 < K2DIM) ? (k2 + 2) : (K2DIM - 2);
                const float* wk = wbase + (size_t)k2n * 1280;
#pragma unroll
                for (int g = 0; g < 5; ++g)
                    wva[g] = *(const float4*)(wk + g * 256);
                a0a = *(const f32x2*)(xr0 + k2n * 2);
                a1a = *(const f32x2*)(xr1 + k2n * 2);
            }
            // compute k2+1 from set B
#pragma unroll
            for (int g = 0; g < 5; ++g) {
                f32x2 we = {wvb[g].x, wvb[g].z};
                f32x2 wo = {wvb[g].y, wvb[g].w};
                acc[0][g] += f32x2{a0b.x, a0b.x} * we;
                acc[0][g] += f32x2{a0b.y, a0b.y} * wo;
                acc[1][g] += f32x2{a1b.x, a1b.x} * we;
                acc[1][g] += f32x2{a1b.y, a1b.y} * wo;
            }
        }

        // ---- gate math + state writes ----
        const size_t ru = (slotR + (size_t)(i - 1)) * 4096;
        const size_t rl = (slotR + (size_t)i) * 4096;
        const size_t wb = (slotW + (size_t)i) * 4096;
#pragma unroll
        for (int cc = 0; cc < 2; ++cc) {
            const int col = cb0 + cc;
            const float wciv = Wci[d * HDIM + col];
            const float wf1v = Wf1[d * HDIM + col];
            const float wf2v = Wf2[d * HDIM + col];
            const float wcov = Wco[d * HDIM + col];
#pragma unroll
            for (int rr = 0; rr < 2; ++rr) {
                const int b = 2 * tr + rr;
                float cu = (i > 0) ? c_par[ru + b * 128 + col] : 0.f;
                float cl = (j > 0) ? c_par[rl + b * 128 + col] : 0.f;
                float ig = sigmoidf_(acc[rr][0][cc] + wciv * (cu + cl));
                float f1 = sigmoidf_(acc[rr][1][cc] + wf1v * cu);
                float f2 = sigmoidf_(acc[rr][2][cc] + wf2v * cl);
                float cn = f1 * cu + f2 * cl + ig * tanhf_(acc[rr][3][cc]);
                float oo = sigmoidf_(acc[rr][4][cc] + wcov * cn);
                float hn = oo * tanhf_(cn);
                c_par[wb + b * 128 + col] = cn;
                h_par[wb + b * 128 + col] = hn;
            }
        }
    } else {
        // ---------------- fused conv block (diagonal s-1) ----------------
        int cb2 = blk - nstep;
        int btc = cb2 & 3, cip = cb2 >> 2;
        int ip = i0p + cip, jp = (s - 1) - ip;
        float* hs = smem;  // reuse: 8 x 512 f32 (16 KB)

        for (int f = t; f < 1024; f += 256) {  // 1024 float4
            int dd = f >> 8, rem = f & 255;
            int bb = rem >> 5, k4 = rem & 31;
            float4 v = *(const float4*)(
                h_par + ((size_t)(parR * 4 + dd) * 64 + ip) * 4096 +
                (btc * 8 + bb) * 128 + k4 * 4);
            *(float4*)&hs[bb * 512 + dd * 128 + k4 * 4] = v;
        }
        __syncthreads();

        const int o = t & 127, half = t >> 7;
        float acc[4];
#pragma unroll
        for (int q = 0; q < 4; ++q) acc[q] = b_conv[o];
#pragma unroll 4
        for (int c = 0; c < 512; ++c) {
            float wv = Wct[c * 128 + o];
#pragma unroll
            for (int q = 0; q < 4; ++q)
                acc[q] = fmaf(hs[(half * 4 + q) * 512 + c], wv, acc[q]);
        }
#pragma unroll
        for (int q = 0; q < 4; ++q) {
            int b = btc * 8 + half * 4 + q;
            out[(size_t)(b * 128 + o) * 4096 + ip * 64 + jp] = acc[q];
        }
    }
}

// ---------------------------------------------------------------------------
extern "C" void kernel_launch(void* const* d_in, const int* in_sizes, int n_in,
                              void* d_out, int out_size, void* d_ws,
                              size_t ws_size, hipStream_t stream) {
    const float* x = (const float*)d_in[0];
    const float* W_lin = (const float*)d_in[1];
    const float* b_lin = (const float*)d_in[2];
    const float* Wci = (const float*)d_in[3];
    const float* Wf1 = (const float*)d_in[4];
    const float* Wf2 = (const float*)d_in[5];
    const float* Wco = (const float*)d_in[6];
    const float* W_conv = (const float*)d_in[7];
    const float* b_conv = (const float*)d_in[8];
    float* out = (float*)d_out;

    // workspace (floats), ~37 MB (proven size)
    const size_t N_PAR = 2ull * 4 * 64 * 32 * 128;  // 2,097,152
    const size_t N_WT = 4ull * KDIM * ZDIM;         //   737,280
    const size_t N_WCT = 512ull * 128;              //    65,536
    const size_t N_XT = 4096ull * 1024;             // 4,194,304
    float* h_par = (float*)d_ws;
    float* c_par = h_par + N_PAR;
    float* Wt2 = c_par + N_PAR;
    float* Wct = Wt2 + N_WT;
    float* x_t = Wct + N_WCT;
    size_t need = (2 * N_PAR + N_WT + N_WCT + N_XT) * 4ull;
    if (ws_size < need) {  // visible failure signature: out = 1e6
        fill_sentinel<<<(out_size + 255) / 256, 256, 0, stream>>>(out);
        return;
    }

    prep_weights<<<3136, 256, 0, stream>>>(W_lin, W_conv, Wt2, Wct);
    transpose_x<<<1024, 256, 0, stream>>>(x, x_t);

    for (int s = 0; s <= 127; ++s) {
        int i0 = 0, nc = 0;
        if (s <= 126) {
            i0 = s > 63 ? s - 63 : 0;
            int i1 = s < 63 ? s : 63;
            nc = i1 - i0 + 1;
        }
        int i0p = 0, ncp = 0;
        if (s >= 1) {
            int sp = s - 1;
            i0p = sp > 63 ? sp - 63 : 0;
            int i1p = sp < 63 ? sp : 63;
            ncp = i1p - i0p + 1;
        }
        int nstep = (s <= 126) ? 16 * nc : 0;
        int nconv = 4 * ncp;
        fused_step<<<nstep + nconv, 256, 0, stream>>>(
            x_t, Wt2, b_lin, Wci, Wf1, Wf2, Wco, Wct, b_conv, h_par, c_par,
            out, s, i0, nc, i0p, ncp, nstep);
    }
}